// Round 11
// baseline (44.885 us; speedup 1.0000x reference)
//
#include <hip/hip_runtime.h>
#include <stdint.h>

#define MARGIN 0.3f
#define NROWS 4096
#define DIM   2048
#define ROWB  1024                  // fp4: DIM/2 bytes per row
#define PLANE (NROWS * 16)          // 65536 B: one 16B-column plane
#define KSTEP (4 * PLANE)           // byte stride between K-steps (4 planes)
#define BT    128
#define NB    (NROWS / BT)          // 32
#define NBLK  (NB * (NB + 1) / 2)   // 528 (divisible by 8 -> clean XCD swizzle)

typedef float f32x4 __attribute__((ext_vector_type(4)));
typedef int   i32x4 __attribute__((ext_vector_type(4)));
typedef int   i32x8 __attribute__((ext_vector_type(8)));
typedef short s16x8 __attribute__((ext_vector_type(8)));

__device__ __forceinline__ ushort f32_to_bf16(float f) {
  uint32_t u = __float_as_uint(f);
  return (ushort)((u + 0x7FFFu + ((u >> 16) & 1u)) >> 16);
}

// e2m1 quantizer, RNE to grid {0,.5,1,1.5,2,3,4,6}, clamp at 6.
__device__ __forceinline__ unsigned f32_to_fp4(float y) {
  unsigned s = (__float_as_uint(y) >> 31) << 3;
  float a = fabsf(y);
  unsigned c;
  if      (a < 0.25f) c = 0;
  else if (a < 0.75f) c = 1;
  else if (a < 1.25f) c = 2;
  else if (a < 1.75f) c = 3;
  else if (a < 2.5f)  c = 4;
  else if (a < 3.5f)  c = 5;
  else if (a < 5.0f)  c = 6;
  else                c = 7;
  return s | c;
}

// ---------------------------------------------------------------------------
// prep: row L2-norm. FLY=0: write normalized fp4(e2m1) matrix, 16B-PLANE-MAJOR
// (transposed at 16B granularity): byte-group g of row r lands at
// g*PLANE + r*16. Value scale 2^6 (undone by the MFMA scale operand).
// FLY=1: write 1/norm. Also zeroes the accumulators.
// ---------------------------------------------------------------------------
template <int FLY>
__global__ __launch_bounds__(256) void prep_kernel(const float* __restrict__ in,
                                                   unsigned char* __restrict__ pn,
                                                   float* __restrict__ invn,
                                                   float* __restrict__ accum) {
  const int row = blockIdx.x;
  const int tid = threadIdx.x;
  if (row == 0 && tid == 0) { accum[0] = 0.f; accum[1] = 0.f; }

  const float4* rp = (const float4*)(in + (size_t)row * DIM);
  float4 v0 = rp[tid * 2];
  float4 v1 = rp[tid * 2 + 1];
  float ss = v0.x*v0.x + v0.y*v0.y + v0.z*v0.z + v0.w*v0.w
           + v1.x*v1.x + v1.y*v1.y + v1.z*v1.z + v1.w*v1.w;
  #pragma unroll
  for (int off = 32; off; off >>= 1) ss += __shfl_down(ss, off);

  __shared__ float wred[4];
  __shared__ float stot;
  const int lane = tid & 63, w = tid >> 6;
  if (lane == 0) wred[w] = ss;
  __syncthreads();
  if (tid == 0) stot = wred[0] + wred[1] + wred[2] + wred[3];
  __syncthreads();
  const float inv = 1.0f / fmaxf(sqrtf(stot), 1e-12f);

  if (FLY) {
    if (tid == 0) invn[row] = inv;
  } else {
    const float sc = inv * 64.0f;            // pre-scale by 2^6
    float e[8] = {v0.x, v0.y, v0.z, v0.w, v1.x, v1.y, v1.z, v1.w};
    uint32_t u = 0;
    #pragma unroll
    for (int j = 0; j < 4; ++j) {
      unsigned lo = f32_to_fp4(e[2*j]   * sc);
      unsigned hi = f32_to_fp4(e[2*j+1] * sc);
      u |= (lo | (hi << 4)) << (8 * j);
    }
    // this thread's 4 fp4-bytes = bytes [tid*4, tid*4+4) of the row
    const int plane = tid >> 2;              // 16B group index 0..63
    const int sub   = (tid & 3) * 4;         // byte offset within the 16B
    *(uint32_t*)(pn + (size_t)plane * PLANE + (size_t)row * 16 + sub) = u;
  }
}

// ---------------------------------------------------------------------------
// tri_gemm: one block per upper-triangular 128x128 super-tile of sim = Pn Pn^T.
// fp4 e2m1 via mfma_scale_f32_16x16x128_f8f6f4 (cbsz=blgp=4), scale bytes
// 0x79 = 2^-6 on both operands -> acc = sim directly.
// 256 threads = 4 waves (2x2), wave tile 64x64 (4x4 frags), 16 K-steps.
// NO LDS, NO BARRIERS in the K-loop: R6/R9/R10 showed the block-wide
// stage->vmcnt(0)->barrier chain is the ~43us critical path regardless of
// bytes/steps. Fragments load straight from the plane-major fp4 matrix
// (16 lanes x 16B contiguous per quarter-wave), manually modulo-2 pipelined;
// the compiler emits per-load counted vmcnt for register loads.
// ---------------------------------------------------------------------------
__device__ __forceinline__ void ld8(const unsigned char* __restrict__ p,
                                    uint32_t voA, uint32_t voB,
                                    i32x4 fa[4], i32x4 fb[4]) {
  #pragma unroll
  for (int m = 0; m < 4; ++m) {
    fa[m] = *(const i32x4*)(p + voA + m * 256);   // +16 rows per m
    fb[m] = *(const i32x4*)(p + voB + m * 256);
  }
}

__device__ __forceinline__ void mm16(const i32x4 fa[4], const i32x4 fb[4],
                                     f32x4 acc[4][4]) {
  const i32x4 z4 = {0, 0, 0, 0};
  #pragma unroll
  for (int m = 0; m < 4; ++m) {
    i32x8 am = __builtin_shufflevector(fa[m], z4, 0, 1, 2, 3, 4, 5, 6, 7);
    #pragma unroll
    for (int n = 0; n < 4; ++n) {
      i32x8 bn = __builtin_shufflevector(fb[n], z4, 0, 1, 2, 3, 4, 5, 6, 7);
      acc[m][n] = __builtin_amdgcn_mfma_scale_f32_16x16x128_f8f6f4(
          am, bn, acc[m][n],
          4, 4,                      // cbsz=fp4(e2m1), blgp=fp4(e2m1)
          0, 0x79797979,             // scale_a: e8m0 = 2^-6 everywhere
          0, 0x79797979);            // scale_b: e8m0 = 2^-6 everywhere
    }
  }
}

__global__ __launch_bounds__(256) void tri_gemm(const unsigned char* __restrict__ pn,
                                                float* __restrict__ accum) {
  // XCD-aware bijective swizzle (NBLK % 8 == 0)
  const int b = blockIdx.x;
  int t = (b & 7) * (NBLK / 8) + (b >> 3);
  int bi = 0;
  while (t >= NB - bi) { t -= NB - bi; ++bi; }
  const int bj = bi + t;

  const int tid  = threadIdx.x;
  const int lane = tid & 63;
  const int w    = tid >> 6;          // 0..3
  const int wr   = w >> 1;            // 0..1
  const int wc   = w & 1;             // 0..1
  const int fr   = lane & 15;         // fragment row within 16
  const int gq   = lane >> 4;         // 16B k-group within the 64B K-step

  f32x4 acc[4][4] = {};
  const int rowA = bi * BT, rowB = bj * BT;

  // per-lane byte offsets into the plane-major fp4 matrix
  uint32_t voA = (uint32_t)gq * PLANE + (uint32_t)(rowA + wr * 64 + fr) * 16;
  uint32_t voB = (uint32_t)gq * PLANE + (uint32_t)(rowB + wc * 64 + fr) * 16;

  i32x4 fa0[4], fb0[4], fa1[4], fb1[4];

  // prologue: K-step 0
  ld8(pn, voA, voB, fa0, fb0);
  voA += KSTEP; voB += KSTEP;

  #pragma unroll 1
  for (int i = 0; i < 8; ++i) {
    // load step 2i+1 while computing step 2i
    ld8(pn, voA, voB, fa1, fb1);
    voA += KSTEP; voB += KSTEP;
    mm16(fa0, fb0, acc);
    // load step 2i+2 while computing step 2i+1 (skip past-the-end load)
    if (i != 7) {
      ld8(pn, voA, voB, fa0, fb0);
      voA += KSTEP; voB += KSTEP;
    }
    mm16(fa1, fb1, acc);
  }

  // ---- epilogue: mask + reduce (C/D layout is shape-determined) ----
  float lsum = 0.f, lcnt = 0.f;
  const int gib = rowA + wr * 64;
  const int gjb = rowB + wc * 64;
  #pragma unroll
  for (int m = 0; m < 4; ++m) {
    #pragma unroll
    for (int n = 0; n < 4; ++n) {
      #pragma unroll
      for (int r = 0; r < 4; ++r) {
        int gi = gib + m * 16 + (lane >> 4) * 4 + r;
        int gj = gjb + n * 16 + (lane & 15);
        float s = acc[m][n][r];
        if (gi < gj && s > MARGIN) { lsum += s - MARGIN; lcnt += 1.f; }
      }
    }
  }
  #pragma unroll
  for (int off = 32; off; off >>= 1) {
    lsum += __shfl_down(lsum, off);
    lcnt += __shfl_down(lcnt, off);
  }
  __shared__ float rs[4], rc[4];
  if (lane == 0) { rs[w] = lsum; rc[w] = lcnt; }
  __syncthreads();
  if (tid == 0) {
    atomicAdd(&accum[0], rs[0] + rs[1] + rs[2] + rs[3]);
    atomicAdd(&accum[1], rc[0] + rc[1] + rc[2] + rc[3]);
  }
}

// ---------------------------------------------------------------------------
// Fallback (tiny workspace): bf16 on-the-fly convert, 256 threads / 4 waves,
// single-buffer, BK=64 bf16 (verified R2 structure), 128x128 tiles.
// ---------------------------------------------------------------------------
__global__ __launch_bounds__(256) void tri_gemm_fly(const float* __restrict__ inF,
                                                    const float* __restrict__ invn,
                                                    float* __restrict__ accum) {
  enum { FBK = 64 };
  int t = blockIdx.x, bi = 0;
  while (t >= NB - bi) { t -= NB - bi; ++bi; }
  const int bj = bi + t;

  __shared__ __align__(16) ushort Asm[BT * FBK];
  __shared__ __align__(16) ushort Bsm[BT * FBK];

  const int tid  = threadIdx.x;
  const int lane = tid & 63;
  const int w    = tid >> 6;
  const int wr   = w >> 1, wc = w & 1;

  f32x4 acc[4][4] = {};
  const int rowA = bi * BT, rowB = bj * BT;

  for (int k0 = 0; k0 < DIM; k0 += FBK) {
    if (k0) __syncthreads();
    #pragma unroll
    for (int p = 0; p < 8; ++p) {
      int c   = p * 256 + tid;
      int isB = c >> 10;
      int cc  = c & 1023;
      int r   = cc >> 3;
      int s   = cc & 7;
      const int grow = (isB ? rowB : rowA) + r;
      const float4* src = (const float4*)(inF + (size_t)grow * DIM + k0 + s * 8);
      float4 v0 = src[0], v1 = src[1];
      int4 pack;
      ushort* h = (ushort*)&pack;
      h[0] = f32_to_bf16(v0.x); h[1] = f32_to_bf16(v0.y);
      h[2] = f32_to_bf16(v0.z); h[3] = f32_to_bf16(v0.w);
      h[4] = f32_to_bf16(v1.x); h[5] = f32_to_bf16(v1.y);
      h[6] = f32_to_bf16(v1.z); h[7] = f32_to_bf16(v1.w);
      *(int4*)((isB ? Bsm : Asm) + r * FBK + (s ^ (r & 7)) * 8) = pack;
    }
    __syncthreads();

    s16x8 af[2][4], bfv[2][4];
    const int fr = lane & 15, hi = lane >> 4;
    #pragma unroll
    for (int kk = 0; kk < 2; ++kk)
      #pragma unroll
      for (int m = 0; m < 4; ++m) {
        const int ra = wr * 64 + m * 16 + fr;
        af[kk][m] = *(const s16x8*)(Asm + ra * FBK + ((kk * 4 + hi) ^ (ra & 7)) * 8);
        const int rb = wc * 64 + m * 16 + fr;
        bfv[kk][m] = *(const s16x8*)(Bsm + rb * FBK + ((kk * 4 + hi) ^ (rb & 7)) * 8);
      }
    #pragma unroll
    for (int kk = 0; kk < 2; ++kk)
      #pragma unroll
      for (int m = 0; m < 4; ++m)
        #pragma unroll
        for (int n = 0; n < 4; ++n)
          acc[m][n] = __builtin_amdgcn_mfma_f32_16x16x32_bf16(af[kk][m], bfv[kk][n],
                                                              acc[m][n], 0, 0, 0);
  }

  float lsum = 0.f, lcnt = 0.f;
  const int gib = rowA + wr * 64;
  const int gjb = rowB + wc * 64;
  #pragma unroll
  for (int m = 0; m < 4; ++m)
    #pragma unroll
    for (int n = 0; n < 4; ++n)
      #pragma unroll
      for (int r = 0; r < 4; ++r) {
        int gi = gib + m * 16 + (lane >> 4) * 4 + r;
        int gj = gjb + n * 16 + (lane & 15);
        float s = acc[m][n][r] * invn[gi] * invn[gj];
        if (gi < gj && s > MARGIN) { lsum += s - MARGIN; lcnt += 1.f; }
      }
  #pragma unroll
  for (int off = 32; off; off >>= 1) {
    lsum += __shfl_down(lsum, off);
    lcnt += __shfl_down(lcnt, off);
  }
  __shared__ float rs[4], rc[4];
  if (lane == 0) { rs[w] = lsum; rc[w] = lcnt; }
  __syncthreads();
  if (tid == 0) {
    atomicAdd(&accum[0], rs[0] + rs[1] + rs[2] + rs[3]);
    atomicAdd(&accum[1], rc[0] + rc[1] + rc[2] + rc[3]);
  }
}

__global__ void finalize_kernel(const float* __restrict__ accum, float* __restrict__ out) {
  if (threadIdx.x == 0) out[0] = (accum[1] < 0.5f) ? 0.0f : accum[0] / accum[1];
}

extern "C" void kernel_launch(void* const* d_in, const int* in_sizes, int n_in,
                              void* d_out, int out_size, void* d_ws, size_t ws_size,
                              hipStream_t stream) {
  const float* in = (const float*)d_in[0];
  float* out = (float*)d_out;
  const size_t pn_bytes = (size_t)NROWS * ROWB;   // fp4: 4.2 MB (64 planes)

  if (ws_size >= pn_bytes + 2 * sizeof(float)) {
    unsigned char* pn = (unsigned char*)d_ws;
    float* accum = (float*)((char*)d_ws + pn_bytes);
    prep_kernel<0><<<NROWS, 256, 0, stream>>>(in, pn, nullptr, accum);
    tri_gemm<<<NBLK, 256, 0, stream>>>(pn, accum);
    finalize_kernel<<<1, 64, 0, stream>>>(accum, out);
  } else {
    float* invn  = (float*)d_ws;
    float* accum = (float*)((char*)d_ws + NROWS * sizeof(float));
    prep_kernel<1><<<NROWS, 256, 0, stream>>>(in, nullptr, invn, accum);
    tri_gemm_fly<<<NBLK, 256, 0, stream>>>(in, invn, accum);
    finalize_kernel<<<1, 64, 0, stream>>>(accum, out);
  }
}